// Round 6
// baseline (135.457 us; speedup 1.0000x reference)
//
#include <hip/hip_runtime.h>
#include <math.h>

// Problem: B=8, C=256, N=H*W=1024, nh=8, dk=dv=32. fp32 in/out, bf16 ws.
// Round 23: occupancy + reg-prefetch staging for K1/K3 (K2's proven pattern).
//   K1 qkv : 1-head blocks, grid (16,8,8)=1024 (was 512); W chunk
//            reg-prefetched one ks ahead (loads overlap MFMA, cheap barriers).
//   K2 attn: r22 verbatim (swapped QK^T, zero-LDS P).
//   K3 oproj: grid (64,8)=512 16-n self-contained slabs (in-place safe);
//            Wo chunk reg-prefetched, single LDS buffer, 28.9KB.
typedef unsigned short u16;
typedef __attribute__((ext_vector_type(8))) unsigned short u16x8;
typedef __attribute__((ext_vector_type(8))) short s16x8;   // MFMA A/B frag
typedef __attribute__((ext_vector_type(4))) float f32x4;   // MFMA C/D

// logits scale 1/sqrt(32) folded with log2(e) so softmax uses exp2 directly
#define QK_SCALE (0.17677669529663687f * 1.4426950408889634f)

__device__ __forceinline__ unsigned cvt2(float lo, float hi) {
  unsigned r;  // D[15:0]=bf16_rne(lo), D[31:16]=bf16_rne(hi)
  asm("v_cvt_pk_bf16_f32 %0, %1, %2" : "=v"(r) : "v"(lo), "v"(hi));
  return r;
}
__device__ __forceinline__ u16 f2bf(float f) { return (u16)cvt2(f, f); }
__device__ __forceinline__ u16x8 ld16(const void* p) { u16x8 v; __builtin_memcpy(&v, p, 16); return v; }
__device__ __forceinline__ void st16(void* p, u16x8 v) { __builtin_memcpy(p, &v, 16); }
__device__ __forceinline__ void st4(void* p, unsigned v) { __builtin_memcpy(p, &v, 4); }
__device__ __forceinline__ void st8(void* p, unsigned lo, unsigned hi) {
  unsigned long long v = ((unsigned long long)hi << 32) | (unsigned long long)lo;
  __builtin_memcpy(p, &v, 8);
}
__device__ __forceinline__ f32x4 ldf4(const void* p) { f32x4 v; __builtin_memcpy(&v, p, 16); return v; }
__device__ __forceinline__ s16x8 frag16(const void* p) { s16x8 v; __builtin_memcpy(&v, p, 16); return v; }
__device__ __forceinline__ s16x8 pack8(f32x4 lo, f32x4 hi) {
  union { unsigned u[4]; s16x8 s; } c;
  c.u[0] = cvt2(lo.x, lo.y); c.u[1] = cvt2(lo.z, lo.w);
  c.u[2] = cvt2(hi.x, hi.y); c.u[3] = cvt2(hi.z, hi.w);
  return c.s;
}

// ---------------------------------------------------------------------------
// K1: QKV projection via MFMA. Grid (16 nt, 8 h, 8 b) = 1024 blocks, 256 thr.
// Block: head h, 64-n tile. Wave w = n-subtile (16 n). K=256 in 8 ks of 32.
// LDS 41.3KB (3 blocks/CU): xt[64][264] (x^T, XOR col swizzle) + wlds[96][40].
// W chunk (96 rows x 32c) is REG-PREFETCHED: unit u=matrix (Wq/Wk/Wv),
// row = t>>3, 8 lanes x 16B = coalesced 128B segments. Per ks: barrier,
// 3 st8 from regs, barrier, issue ks+1 loads, 7 frag reads + 6 MFMA, cvt.
// Epilogue: q,k -> [bh][n][d] (q pre-scaled); v -> [bh][d][nperm] with the
// PV-matched key permutation (64-chunk-closed; see K2).
// ---------------------------------------------------------------------------
__global__ __launch_bounds__(256) void r23_qkv(
    const float* __restrict__ x,
    const float* __restrict__ Wq, const float* __restrict__ bq,
    const float* __restrict__ Wk, const float* __restrict__ bk,
    const float* __restrict__ Wv, const float* __restrict__ bv,
    u16* __restrict__ qo, u16* __restrict__ ko, u16* __restrict__ vo)
{
  __shared__ u16 xt[64][264];    // [n][c^msk(n)], row stride 528B
  __shared__ u16 wlds[96][40];   // rows: 0-31 Wq, 32-63 Wk, 64-95 Wv

  const int t = threadIdx.x;
  const int ntile = blockIdx.x, h = blockIdx.y, b = blockIdx.z;
  const int n0 = ntile * 64;
  const int w = t >> 6, lane = t & 63, l15 = lane & 15, quad = lane >> 4;
  const int oct = t & 7;

  {  // stage x^T, coalesced: pass p covers channels p*16..p*16+15.
    const int i = t & 15, co = t >> 4;           // i: n-quad, co: c within pass
    const float* xb = x + ((size_t)b * 256 + co) * 1024 + n0 + i * 4;
    const int msk = (i & 7) << 3;                // n>>2 == i
#pragma unroll
    for (int p = 0; p < 16; ++p) {
      const f32x4 a = ldf4(xb + (size_t)p * 16 * 1024);
      const int c = p * 16 + co;
#pragma unroll
      for (int j = 0; j < 4; ++j)
        xt[i * 4 + j][(c ^ msk)] = f2bf(a[j]);
    }
  }

  // W reg-prefetch: unit u = matrix u, row rr = t>>3, cols oct*4..+3
  const int rr = t >> 3;
  const float* wsrc[3];
  wsrc[0] = Wq + (size_t)(h * 32 + rr) * 256 + oct * 4;
  wsrc[1] = Wk + (size_t)(h * 32 + rr) * 256 + oct * 4;
  wsrc[2] = Wv + (size_t)(h * 32 + rr) * 256 + oct * 4;
  unsigned wreg[3][2];
#pragma unroll
  for (int u = 0; u < 3; ++u) {
    const f32x4 a = ldf4(wsrc[u]);               // ks = 0
    wreg[u][0] = cvt2(a.x, a.y); wreg[u][1] = cvt2(a.z, a.w);
  }

  f32x4 acc[6];
#pragma unroll
  for (int i = 0; i < 6; ++i) acc[i] = (f32x4){0.f, 0.f, 0.f, 0.f};

  const int nrow = w * 16 + l15;
  const int bmsk = ((nrow >> 2) & 7) << 3;

  for (int ks = 0; ks < 8; ++ks) {
    __syncthreads();   // readers of wlds done (and xt staged, on ks=0)
#pragma unroll
    for (int u = 0; u < 3; ++u)
      st8(&wlds[u * 32 + rr][oct * 4], wreg[u][0], wreg[u][1]);
    __syncthreads();

    f32x4 nx[3];
    if (ks < 7) {
#pragma unroll
      for (int u = 0; u < 3; ++u) nx[u] = ldf4(wsrc[u] + (ks + 1) * 32);
    }

    const s16x8 bfrag = frag16(&xt[nrow][(ks * 32 + quad * 8) ^ bmsk]);
#pragma unroll
    for (int mt = 0; mt < 6; ++mt) {
      const s16x8 af = frag16(&wlds[mt * 16 + l15][quad * 8]);
      acc[mt] = __builtin_amdgcn_mfma_f32_16x16x32_bf16(af, bfrag, acc[mt], 0, 0, 0);
    }

    if (ks < 7) {
#pragma unroll
      for (int u = 0; u < 3; ++u) {
        wreg[u][0] = cvt2(nx[u].x, nx[u].y);
        wreg[u][1] = cvt2(nx[u].z, nx[u].w);
      }
    }
  }

  // epilogue: C/D row = quad*4+rr2 (d within 16), col = l15 (n within 16)
  const int n = n0 + w * 16 + l15;
  const int sig = n & 127;
  const int ntn = sig >> 4, q4 = (sig >> 2) & 3, rn = sig & 3;
  const int nperm = (n & ~127) | ((ntn >> 1) << 5) | (q4 << 3) | ((ntn & 1) << 2) | rn;
  const size_t bh = (size_t)(b * 8 + h);
  u16* qrow = qo + (bh * 1024 + n) * 32;
  u16* krow = ko + (bh * 1024 + n) * 32;
#pragma unroll
  for (int half = 0; half < 2; ++half) {
    const int d0 = half * 16 + quad * 4;
    const f32x4 aq = acc[0 + half];
    const f32x4 ak = acc[2 + half];
    const f32x4 av = acc[4 + half];
    st4(qrow + d0,     cvt2((aq.x + bq[h * 32 + d0 + 0]) * QK_SCALE,
                            (aq.y + bq[h * 32 + d0 + 1]) * QK_SCALE));
    st4(qrow + d0 + 2, cvt2((aq.z + bq[h * 32 + d0 + 2]) * QK_SCALE,
                            (aq.w + bq[h * 32 + d0 + 3]) * QK_SCALE));
    st4(krow + d0,     cvt2(ak.x + bk[h * 32 + d0 + 0],
                            ak.y + bk[h * 32 + d0 + 1]));
    st4(krow + d0 + 2, cvt2(ak.z + bk[h * 32 + d0 + 2],
                            ak.w + bk[h * 32 + d0 + 3]));
#pragma unroll
    for (int rr2 = 0; rr2 < 4; ++rr2) {
      const int d = d0 + rr2;
      vo[(bh * 32 + d) * 1024 + nperm] = f2bf(av[rr2] + bv[h * 32 + d]);
    }
  }
}

// ---------------------------------------------------------------------------
// K2: flash attention, swapped QK^T, zero-LDS P (r22 verbatim).
// Grid (16 qtiles, 64 bh); 4 waves x 16 queries. QK: mfma(K,Q) -> lane holds
// S^T[32 keys][1 query]. Softmax in-lane + shfl_xor(16,32). PV: O^T = V^T*P^T
// with B-frag packed from the lane's own registers (V key-permuted by K1).
// K/V staged via reg-prefetch one chunk ahead; 2 barriers/iter.
// ---------------------------------------------------------------------------
__global__ __launch_bounds__(256) void r23_attn(
    const u16* __restrict__ qw, const u16* __restrict__ kw,
    const u16* __restrict__ vw, float* __restrict__ out)
{
  __shared__ u16 klds[128][40];   // [key][d]   10240B
  __shared__ u16 vlds[32][136];   // [d][kperm]  8704B

  const int t = threadIdx.x;
  const int qtile = blockIdx.x;
  const int bh = blockIdx.y;
  const int w = t >> 6, lane = t & 63, l15 = lane & 15, quad = lane >> 4;

  // B-frag: B[k=quad*8+j][n=l15] = Q[query w*16+l15][d=quad*8+j]
  const s16x8 qfrag = frag16(
      qw + ((size_t)bh * 1024 + qtile * 64 + w * 16 + l15) * 32 + quad * 8);

  // staging addresses: K row t>>1 (2 thr/row), V row t>>3 (8 thr/row)
  const u16* kbase = kw + ((size_t)bh * 1024 + (t >> 1)) * 32 + (t & 1) * 16;
  const u16* vbase = vw + ((size_t)bh * 32 + (t >> 3)) * 1024 + (t & 7) * 16;

  u16x8 gk0 = ld16(kbase), gk1 = ld16(kbase + 8);
  u16x8 gv0 = ld16(vbase), gv1 = ld16(vbase + 8);

  f32x4 o0 = {0.f, 0.f, 0.f, 0.f}, o1 = {0.f, 0.f, 0.f, 0.f};
  float mrun = -1e30f, lrun = 0.f;

  for (int kb = 0; kb < 8; ++kb) {
    if (kb) __syncthreads();       // all waves done reading previous chunk
    st16(&klds[t >> 1][(t & 1) * 16], gk0);
    st16(&klds[t >> 1][(t & 1) * 16 + 8], gk1);
    st16(&vlds[t >> 3][(t & 7) * 16], gv0);
    st16(&vlds[t >> 3][(t & 7) * 16 + 8], gv1);
    if (kb < 7) {                  // prefetch next chunk into regs (T14)
      const u16* kn = kbase + (size_t)(kb + 1) * (128 * 32);
      const u16* vn = vbase + (size_t)(kb + 1) * 128;
      gk0 = ld16(kn); gk1 = ld16(kn + 8);
      gv0 = ld16(vn); gv1 = ld16(vn + 8);
    }
    __syncthreads();               // staging visible

    // QK^T swapped: s[nt2][r] = S[key nt2*16+quad*4+r][query w*16+l15]
    f32x4 s[8];
    const f32x4 zz = {0.f, 0.f, 0.f, 0.f};
#pragma unroll
    for (int nt2 = 0; nt2 < 8; ++nt2) {
      const s16x8 kf = frag16(&klds[nt2 * 16 + l15][quad * 8]);
      s[nt2] = __builtin_amdgcn_mfma_f32_16x16x32_bf16(kf, qfrag, zz, 0, 0, 0);
    }

    // online softmax: in-lane over 32 keys + cross-quad reduce (xor 16,32)
    float mx = fmaxf(fmaxf(s[0][0], s[0][1]), fmaxf(s[0][2], s[0][3]));
#pragma unroll
    for (int nt2 = 1; nt2 < 8; ++nt2)
      mx = fmaxf(mx, fmaxf(fmaxf(s[nt2][0], s[nt2][1]),
                           fmaxf(s[nt2][2], s[nt2][3])));
    mx = fmaxf(mx, __shfl_xor(mx, 16));
    mx = fmaxf(mx, __shfl_xor(mx, 32));
    const float mnew = fmaxf(mrun, mx);
    const float alpha = exp2f(mrun - mnew);
    float rs = 0.f;
#pragma unroll
    for (int nt2 = 0; nt2 < 8; ++nt2) {
#pragma unroll
      for (int r = 0; r < 4; ++r) {
        s[nt2][r] = exp2f(s[nt2][r] - mnew);
        rs += s[nt2][r];
      }
    }
    rs += __shfl_xor(rs, 16);
    rs += __shfl_xor(rs, 32);
    lrun = lrun * alpha + rs;
    mrun = mnew;
#pragma unroll
    for (int r = 0; r < 4; ++r) { o0[r] *= alpha; o1[r] *= alpha; }

    // PV: O^T = V^T * P^T; B-frag slot (quad, j=hi*4+r) = p[2ks+hi][r]
#pragma unroll
    for (int ks = 0; ks < 4; ++ks) {
      const s16x8 pf  = pack8(s[2 * ks], s[2 * ks + 1]);
      const s16x8 vf0 = frag16(&vlds[l15][ks * 32 + quad * 8]);
      const s16x8 vf1 = frag16(&vlds[16 + l15][ks * 32 + quad * 8]);
      o0 = __builtin_amdgcn_mfma_f32_16x16x32_bf16(vf0, pf, o0, 0, 0, 0);
      o1 = __builtin_amdgcn_mfma_f32_16x16x32_bf16(vf1, pf, o1, 0, 0, 0);
    }
  }

  // epilogue: lane holds O^T[d][query l15]; rows are channels -> direct
  // coalesced stores (16 lanes x 4B contiguous per quad-row).
  const float inv = 1.0f / lrun;
  const int b = bh >> 3, hh = bh & 7;
  float* obase = out + ((size_t)b * 256 + hh * 32) * 1024
               + qtile * 64 + w * 16 + l15;
#pragma unroll
  for (int r = 0; r < 4; ++r) {
    obase[(size_t)(quad * 4 + r) * 1024]      = o0[r] * inv;
    obase[(size_t)(16 + quad * 4 + r) * 1024] = o1[r] * inv;
  }
}

// ---------------------------------------------------------------------------
// K3: out-projection via MFMA, in-place on fp32 d_out. Grid (64 nt16, 8 b)
// = 512 blocks, 256 thr. Block: 16-n slab, all 256 oc (self-contained ->
// in-place safe). LDS 28.9KB: o2t[16][264] + wl3[256][40] single buffer,
// Wo chunk REG-PREFETCHED (8 units/thread, coalesced 128B segments).
// Wave w: oc = w*64 + mt*16 (4 mt) x 16 n. Per ks: 4 A + 1 B frags, 4 MFMA.
// ---------------------------------------------------------------------------
__global__ __launch_bounds__(256) void r23_oproj(
    const float* __restrict__ Wo, const float* __restrict__ bo,
    float* __restrict__ out)
{
  __shared__ u16 o2t[16][264];   // [n][c^msk(n)], row stride 528B
  __shared__ u16 wl3[256][40];   // Wo rows, current 32-c chunk

  const int t = threadIdx.x;
  const int nt = blockIdx.x, b = blockIdx.y;
  const int w = t >> 6, lane = t & 63, l15 = lane & 15, quad = lane >> 4;
  const int oct = t & 7;

  {  // stage out-slab^T, coalesced: 4 passes of 64 channels.
    const int nq = t & 3, co = t >> 2;           // nq: n-quad, co: c in pass
    const float* ob = out + ((size_t)b * 256 + co) * 1024 + nt * 16 + nq * 4;
    const int msk = nq << 3;                     // n>>2 == nq
#pragma unroll
    for (int p = 0; p < 4; ++p) {
      const f32x4 a = ldf4(ob + (size_t)p * 64 * 1024);
      const int c = p * 64 + co;
#pragma unroll
      for (int j = 0; j < 4; ++j)
        o2t[nq * 4 + j][(c ^ msk)] = f2bf(a[j]);
    }
  }

  // Wo reg-prefetch: unit u: row = u*32 + (t>>3), cols oct*4..+3
  const int rr = t >> 3;
  const float* wsrc = Wo + (size_t)rr * 256 + oct * 4;
  unsigned wreg[8][2];
#pragma unroll
  for (int u = 0; u < 8; ++u) {
    const f32x4 a = ldf4(wsrc + (size_t)u * 32 * 256);   // ks = 0
    wreg[u][0] = cvt2(a.x, a.y); wreg[u][1] = cvt2(a.z, a.w);
  }

  f32x4 acc[4];
#pragma unroll
  for (int mt = 0; mt < 4; ++mt) acc[mt] = (f32x4){0.f, 0.f, 0.f, 0.f};

  const int bmsk = ((l15 >> 2) & 7) << 3;

  for (int ks = 0; ks < 8; ++ks) {
    __syncthreads();   // readers of wl3 done (and o2t staged, on ks=0)
#pragma unroll
    for (int u = 0; u < 8; ++u)
      st8(&wl3[u * 32 + rr][oct * 4], wreg[u][0], wreg[u][1]);
    __syncthreads();

    f32x4 nx[8];
    if (ks < 7) {
#pragma unroll
      for (int u = 0; u < 8; ++u)
        nx[u] = ldf4(wsrc + (size_t)u * 32 * 256 + (ks + 1) * 32);
    }

    const s16x8 b0 = frag16(&o2t[l15][(ks * 32 + quad * 8) ^ bmsk]);
#pragma unroll
    for (int mt = 0; mt < 4; ++mt) {
      const s16x8 af = frag16(&wl3[w * 64 + mt * 16 + l15][quad * 8]);
      acc[mt] = __builtin_amdgcn_mfma_f32_16x16x32_bf16(af, b0, acc[mt], 0, 0, 0);
    }

    if (ks < 7) {
#pragma unroll
      for (int u = 0; u < 8; ++u) {
        wreg[u][0] = cvt2(nx[u].x, nx[u].y);
        wreg[u][1] = cvt2(nx[u].z, nx[u].w);
      }
    }
  }

  // epilogue: C/D row = quad*4+r (oc), col = l15 (n); coalesced per store
#pragma unroll
  for (int mt = 0; mt < 4; ++mt) {
#pragma unroll
    for (int r = 0; r < 4; ++r) {
      const int oc = w * 64 + mt * 16 + quad * 4 + r;
      out[((size_t)b * 256 + oc) * 1024 + nt * 16 + l15] = acc[mt][r] + bo[oc];
    }
  }
}

// ---------------------------------------------------------------------------
extern "C" void kernel_launch(void* const* d_in, const int* in_sizes, int n_in,
                              void* d_out, int out_size, void* d_ws, size_t ws_size,
                              hipStream_t stream) {
  (void)in_sizes; (void)n_in; (void)out_size; (void)ws_size;
  const float* x  = (const float*)d_in[0];
  const float* Wq = (const float*)d_in[1];
  const float* bq = (const float*)d_in[2];
  const float* Wk = (const float*)d_in[3];
  const float* bk = (const float*)d_in[4];
  const float* Wv = (const float*)d_in[5];
  const float* bv = (const float*)d_in[6];
  const float* Wo = (const float*)d_in[7];
  const float* bo = (const float*)d_in[8];
  float* out = (float*)d_out;

  char* ws = (char*)d_ws;                    // 12 MB
  u16* qw = (u16*)(ws);                      // [bh][n][d] bf16, 4MB
  u16* kw = (u16*)(ws + (4u << 20));         // [bh][n][d] bf16, 4MB
  u16* vw = (u16*)(ws + (8u << 20));         // [bh][d][nperm] bf16, 4MB

  r23_qkv<<<dim3(16, 8, 8), 256, 0, stream>>>(
      x, Wq, bq, Wk, bk, Wv, bv, qw, kw, vw);
  r23_attn<<<dim3(16, 64), 256, 0, stream>>>(qw, kw, vw, out);
  r23_oproj<<<dim3(64, 8), 256, 0, stream>>>(Wo, bo, out);
}